// Round 3
// baseline (3167.164 us; speedup 1.0000x reference)
//
#include <hip/hip_runtime.h>

#define NPTS   100000
#define HW     50          // hidden width == Q
#define NHID   4
#define DTc    0.6f
#define LBc   (-1.0f)
#define UBc    1.0f
#define PPB    64          // points per 256-thread block (4 lanes/point)
#define NBLK   ((2*NPTS + PPB - 1) / PPB)   // 3125 exactly

typedef float v2f __attribute__((ext_vector_type(2)));

// quad_perm broadcast within each 4-lane group (pure VALU, no LDS pipe)
template <int CTRL>
__device__ __forceinline__ float qperm(float v) {
    return __int_as_float(__builtin_amdgcn_mov_dpp(__float_as_int(v), CTRL, 0xF, 0xF, true));
}

// tanh(z) = 1 - 2/(exp(2z)+1): 2 trans ops, saturates correctly
__device__ __forceinline__ float fast_tanh(float z) {
    float e = __expf(2.0f * z);
    return 1.0f - 2.0f * __builtin_amdgcn_rcpf(e + 1.0f);
}

__global__ __launch_bounds__(256) void pinn_kdv_kernel(
    const float* __restrict__ x1, const float* __restrict__ x2,
    const float* __restrict__ W_in, const float* __restrict__ b_in,
    const float* __restrict__ W_hid, const float* __restrict__ b_hid,
    const float* __restrict__ W_out, const float* __restrict__ b_out,
    const float* __restrict__ lambda_1, const float* __restrict__ lambda_2,
    const float* __restrict__ irk_alpha, const float* __restrict__ irk_beta,
    float* __restrict__ out)
{
    // rows 0..49 = alpha, rows 50..51 = 0 (pad), rows 52..55 = beta (replicated)
    // row stride 50 floats -> lane banks (50c+2j) mod 32 = {0,18,4,22}+2j: conflict-free b64
    __shared__ float alpha_lds[56 * HW];

    const int tid = threadIdx.x;
    const int c = tid & 3;                 // derivative channel: 0=u,1=u_x,2=u_xx,3=u_xxx

    for (int i = tid; i < 56 * HW; i += 256) {
        int row = i / HW;
        int col = i - row * HW;
        float v = 0.0f;
        if (row < HW) v = irk_alpha[i];
        else if (row >= 52) v = irk_beta[col];
        alpha_lds[i] = v;
    }
    __syncthreads();

    const float lam1 = lambda_1[0];
    const float lam2 = __expf(lambda_2[0]);

    const int pi = blockIdx.x * PPB + (tid >> 2);    // 0..199999 (grid exact)
    const bool br2 = (pi >= NPTS);
    const float x = br2 ? x2[pi - NPTS] : x1[pi];

    float h[HW];                           // activations in REGISTERS (all idx static)

    // ---- input layer (1 -> 50): z' = g*w, z'' = z''' = 0 ----
    const float xh = 2.0f * (x - LBc) / (UBc - LBc) - 1.0f;
    const float g  = 2.0f / (UBc - LBc);
    #pragma unroll
    for (int j = 0; j < HW; ++j) {
        float w  = W_in[j];                 // wave-uniform -> s_load
        float z0 = __builtin_fmaf(xh, w, b_in[j]);
        float z1 = g * w;
        float t = fast_tanh(z0);
        float tt = t * t;
        float s = 1.0f - tt;
        float z1sq = z1 * z1;
        float h1 = s * z1;
        float h2 = -2.0f * t * s * z1sq;
        float h3 = s * (6.0f * tt - 2.0f) * z1sq * z1;
        h[j] = (c == 0) ? t : (c == 1) ? h1 : (c == 2) ? h2 : h3;
    }

    // ---- 4 hidden layers + output layer (50 -> 50, all tanh) ----
    #pragma unroll 1
    for (int layer = 0; layer <= NHID; ++layer) {
        const bool last = (layer == NHID);
        const float* Wp = last ? W_out : (W_hid + layer * HW * HW);
        const float* bp = last ? b_out : (b_hid + layer * HW);
        const float bm = (c == 0) ? 1.0f : 0.0f;  // bias only on value channel

        v2f zv[HW / 2];                     // packed accumulators -> v_pk_fma_f32
        #pragma unroll
        for (int j = 0; j < HW / 2; ++j) {
            zv[j].x = bm * bp[2 * j];
            zv[j].y = bm * bp[2 * j + 1];
        }

        #pragma unroll
        for (int k = 0; k < HW; ++k) {      // FULL unroll: h[k] stays in registers
            v2f hd; hd.x = h[k]; hd.y = h[k];
            const v2f* wr = reinterpret_cast<const v2f*>(Wp + k * HW);
            #pragma unroll
            for (int j = 0; j < HW / 2; ++j)
                zv[j] = __builtin_elementwise_fma(hd, wr[j], zv[j]);
        }

        // nonlinear step: couple channels via quad broadcasts (register-only DPP)
        #pragma unroll
        for (int j = 0; j < HW; ++j) {
            float zj = (j & 1) ? zv[j >> 1].y : zv[j >> 1].x;   // static component
            float z0b = qperm<0x00>(zj);
            float z1b = qperm<0x55>(zj);
            float z2b = qperm<0xAA>(zj);
            float z3b = qperm<0xFF>(zj);
            float t  = fast_tanh(z0b);
            float tt = t * t;
            float s  = 1.0f - tt;
            float t2 = t + t;
            float z1sq = z1b * z1b;
            float a2 = __builtin_fmaf(-t2, z1sq, z2b);          // z2 - 2t z1^2
            float z1cu = z1sq * z1b;
            float u  = __builtin_fmaf(6.0f, tt, -2.0f);         // 6t^2 - 2
            float z12 = z1b * z2b;
            float t6 = 3.0f * t2;                               // 6t
            float a3 = __builtin_fmaf(u, z1cu,
                        __builtin_fmaf(-t6, z12, z3b));         // u_xxx / s
            float val;
            if (!last) {
                float inner = (c == 1) ? z1b : (c == 2) ? a2 : a3;
                val = (c == 0) ? t : s * inner;
            } else {
                // N_j = -lam1*U*U_x - exp(lam2)*U_xxx (same in all 4 lanes)
                val = __builtin_fmaf(-lam1, t * (s * z1b), -lam2 * (s * a3));
            }
            h[j] = val;
        }
    }

    // ---- IRK: vm[m] = sum_j N_j alpha[4m+c][j]; rows 52..55 = beta -> vm[13] = S
    v2f vm[14];
    #pragma unroll
    for (int m = 0; m < 14; ++m) { vm[m].x = 0.0f; vm[m].y = 0.0f; }

    #pragma unroll
    for (int j2 = 0; j2 < HW / 2; ++j2) {   // FULL unroll: h[] static
        v2f njd; njd.x = h[2 * j2]; njd.y = h[2 * j2 + 1];
        #pragma unroll
        for (int m = 0; m < 14; ++m) {
            v2f av = *reinterpret_cast<const v2f*>(&alpha_lds[(4 * m + c) * HW + 2 * j2]);
            vm[m] = __builtin_elementwise_fma(njd, av, vm[m]);
        }
    }

    const float S = vm[13].x + vm[13].y;
    float acc = 0.0f;
    #pragma unroll
    for (int m = 0; m < 13; ++m) {
        float vs = vm[m].x + vm[m].y;
        float V = br2 ? (S - vs) : vs;
        if (m < 12) {
            acc = __builtin_fmaf(V, V, acc);
        } else {                            // row 48+c: only c<2 are real rows (<50)
            float Vg = (c < 2) ? V : 0.0f;
            acc = __builtin_fmaf(Vg, Vg, acc);
        }
    }
    acc *= DTc * DTc;

    #pragma unroll
    for (int off = 1; off < 64; off <<= 1)
        acc += __shfl_xor(acc, off);

    if ((tid & 63) == 0) atomicAdd(out, acc);
}

extern "C" void kernel_launch(void* const* d_in, const int* in_sizes, int n_in,
                              void* d_out, int out_size, void* d_ws, size_t ws_size,
                              hipStream_t stream) {
    const float* x1        = (const float*)d_in[0];
    const float* x2        = (const float*)d_in[1];
    const float* W_in      = (const float*)d_in[2];
    const float* b_in      = (const float*)d_in[3];
    const float* W_hid     = (const float*)d_in[4];
    const float* b_hid     = (const float*)d_in[5];
    const float* W_out     = (const float*)d_in[6];
    const float* b_out     = (const float*)d_in[7];
    const float* lambda_1  = (const float*)d_in[8];
    const float* lambda_2  = (const float*)d_in[9];
    const float* irk_alpha = (const float*)d_in[10];
    const float* irk_beta  = (const float*)d_in[11];
    float* out = (float*)d_out;

    hipMemsetAsync(out, 0, sizeof(float), stream);   // d_out is poisoned 0xAA
    hipLaunchKernelGGL(pinn_kdv_kernel, dim3(NBLK), dim3(256), 0, stream,
                       x1, x2, W_in, b_in, W_hid, b_hid, W_out, b_out,
                       lambda_1, lambda_2, irk_alpha, irk_beta, out);
}

// Round 4
// 663.648 us; speedup vs baseline: 4.7724x; 4.7724x over previous
//
#include <hip/hip_runtime.h>

#define NPTS   100000
#define HW     50          // hidden width == Q
#define NHID   4
#define DTc    0.6f
#define LBc   (-1.0f)
#define UBc    1.0f
#define PPB    64          // points per 256-thread block (4 lanes/point)
#define NBLK   ((2*NPTS + PPB - 1) / PPB)   // 3125 exactly
#define HSTRIDE 54         // fp16 slab stride: bank stride 27, gcd(27,32)=1 -> free
#define NSCALE 1024.0f     // last-layer N ~1e-5 is fp16-subnormal; store N*1024

// quad_perm broadcast within each 4-lane group (pure VALU, no LDS pipe)
template <int CTRL>
__device__ __forceinline__ float qperm(float v) {
    return __int_as_float(__builtin_amdgcn_mov_dpp(__float_as_int(v), CTRL, 0xF, 0xF, true));
}

// tanh(z) = 1 - 2/(exp(2z)+1): 2 trans ops, saturates correctly
__device__ __forceinline__ float fast_tanh(float z) {
    float e = __expf(2.0f * z);
    return 1.0f - 2.0f * __builtin_amdgcn_rcpf(e + 1.0f);
}

__global__ __launch_bounds__(256, 4) void pinn_kdv_kernel(
    const float* __restrict__ x1, const float* __restrict__ x2,
    const float* __restrict__ W_in, const float* __restrict__ b_in,
    const float* __restrict__ W_hid, const float* __restrict__ b_hid,
    const float* __restrict__ W_out, const float* __restrict__ b_out,
    const float* __restrict__ lambda_1, const float* __restrict__ lambda_2,
    const float* __restrict__ irk_alpha, const float* __restrict__ irk_beta,
    float* __restrict__ out)
{
    // fp16 per-thread activation slice: 256*54*2 = 27648 B
    __shared__ _Float16 h_lds[256 * HSTRIDE];
    // rows 0..49 = alpha, 50..51 = 0 pad, 52..55 = beta replicated: 11200 B
    __shared__ float alpha_lds[56 * HW];
    __shared__ float blk_part[4];          // per-wave partials -> 1 atomic/block

    const int tid = threadIdx.x;
    const int c = tid & 3;                 // derivative channel: 0=u,1=u_x,2=u_xx,3=u_xxx

    for (int i = tid; i < 56 * HW; i += 256) {
        int row = i / HW;
        int col = i - row * HW;
        float v = 0.0f;
        if (row < HW) v = irk_alpha[i];
        else if (row >= 52) v = irk_beta[col];
        alpha_lds[i] = v;
    }
    __syncthreads();

    const float lam1 = lambda_1[0];
    const float lam2 = __expf(lambda_2[0]);

    const int pi = blockIdx.x * PPB + (tid >> 2);    // 0..199999 (grid exact)
    const bool br2 = (pi >= NPTS);
    const float x = br2 ? x2[pi - NPTS] : x1[pi];

    _Float16* myh = &h_lds[tid * HSTRIDE];

    // ---- input layer (1 -> 50): z' = g*w, z'' = z''' = 0 ----
    const float xh = 2.0f * (x - LBc) / (UBc - LBc) - 1.0f;
    const float g  = 2.0f / (UBc - LBc);
    #pragma unroll 2
    for (int j = 0; j < HW; ++j) {
        float w  = W_in[j];                 // wave-uniform -> scalar pipe
        float z0 = __builtin_fmaf(xh, w, b_in[j]);
        float z1 = g * w;
        float t = fast_tanh(z0);
        float tt = t * t;
        float s = 1.0f - tt;
        float z1sq = z1 * z1;
        float h1 = s * z1;
        float h2 = -2.0f * t * s * z1sq;
        float h3 = s * (6.0f * tt - 2.0f) * z1sq * z1;
        float val = (c == 0) ? t : (c == 1) ? h1 : (c == 2) ? h2 : h3;
        myh[j] = (_Float16)val;
    }

    // ---- 4 hidden layers + output layer (50 -> 50, all tanh) ----
    #pragma unroll 1
    for (int layer = 0; layer <= NHID; ++layer) {
        const bool last = (layer == NHID);
        const float* Wp = last ? W_out : (W_hid + layer * HW * HW);
        const float* bp = last ? b_out : (b_hid + layer * HW);

        // bias belongs ONLY to the value channel; derivative channels start at 0
        float z[HW];                        // accumulators, static idx -> registers
        #pragma unroll
        for (int j = 0; j < HW; ++j) z[j] = (c == 0) ? bp[j] : 0.0f;

        #pragma unroll 2
        for (int k = 0; k < HW; ++k) {
            float hk = (float)myh[k];       // ds_read_u16 + cvt, own slice
            const float2* wr2 = reinterpret_cast<const float2*>(Wp + k * HW);
            #pragma unroll
            for (int j2 = 0; j2 < HW / 2; ++j2) {
                float2 w = wr2[j2];
                z[2 * j2]     = __builtin_fmaf(hk, w.x, z[2 * j2]);
                z[2 * j2 + 1] = __builtin_fmaf(hk, w.y, z[2 * j2 + 1]);
            }
        }

        // nonlinear step: couple channels via quad broadcasts (register-only DPP)
        #pragma unroll
        for (int j = 0; j < HW; ++j) {
            float z0b = qperm<0x00>(z[j]);
            float z1b = qperm<0x55>(z[j]);
            float z2b = qperm<0xAA>(z[j]);
            float z3b = qperm<0xFF>(z[j]);
            float t  = fast_tanh(z0b);
            float tt = t * t;
            float s  = 1.0f - tt;
            float t2 = t + t;
            float z1sq = z1b * z1b;
            float a2 = __builtin_fmaf(-t2, z1sq, z2b);          // z2 - 2t z1^2
            float z1cu = z1sq * z1b;
            float u  = __builtin_fmaf(6.0f, tt, -2.0f);         // 6t^2 - 2
            float a3 = __builtin_fmaf(u, z1cu,
                        __builtin_fmaf(-(3.0f * t2), z1b * z2b, z3b));
            float val;
            if (!last) {
                float inner = (c == 1) ? z1b : (c == 2) ? a2 : a3;
                val = (c == 0) ? t : s * inner;
            } else {
                // N_j = -lam1*U*U_x - exp(lam2)*U_xxx (same in all 4 lanes), scaled
                val = NSCALE * __builtin_fmaf(-lam1, t * (s * z1b), -lam2 * (s * a3));
            }
            myh[j] = (_Float16)val;
        }
    }

    // ---- IRK: v[m] = sum_j N'_j alpha[4m+c][j]; rows 52..55 = beta -> v[13] = S'
    float v[14];
    #pragma unroll
    for (int m = 0; m < 14; ++m) v[m] = 0.0f;

    #pragma unroll 1
    for (int j = 0; j < HW; ++j) {
        float nj = (float)myh[j];
        #pragma unroll
        for (int m = 0; m < 14; ++m)
            v[m] = __builtin_fmaf(nj, alpha_lds[(4 * m + c) * HW + j], v[m]);
    }

    const float S = v[13];
    float acc = 0.0f;
    #pragma unroll
    for (int m = 0; m < 13; ++m) {
        float V = br2 ? (S - v[m]) : v[m];
        if (m < 12) {
            acc = __builtin_fmaf(V, V, acc);
        } else {                            // row 48+c: only c<2 are real rows (<50)
            float Vg = (c < 2) ? V : 0.0f;
            acc = __builtin_fmaf(Vg, Vg, acc);
        }
    }
    acc *= (DTc * DTc) / (NSCALE * NSCALE);

    #pragma unroll
    for (int off = 1; off < 64; off <<= 1)
        acc += __shfl_xor(acc, off);

    // one atomic per block: wave leaders -> LDS -> lane 0 of wave 0
    if ((tid & 63) == 0) blk_part[tid >> 6] = acc;
    __syncthreads();
    if (tid == 0)
        atomicAdd(out, blk_part[0] + blk_part[1] + blk_part[2] + blk_part[3]);
}

extern "C" void kernel_launch(void* const* d_in, const int* in_sizes, int n_in,
                              void* d_out, int out_size, void* d_ws, size_t ws_size,
                              hipStream_t stream) {
    const float* x1        = (const float*)d_in[0];
    const float* x2        = (const float*)d_in[1];
    const float* W_in      = (const float*)d_in[2];
    const float* b_in      = (const float*)d_in[3];
    const float* W_hid     = (const float*)d_in[4];
    const float* b_hid     = (const float*)d_in[5];
    const float* W_out     = (const float*)d_in[6];
    const float* b_out     = (const float*)d_in[7];
    const float* lambda_1  = (const float*)d_in[8];
    const float* lambda_2  = (const float*)d_in[9];
    const float* irk_alpha = (const float*)d_in[10];
    const float* irk_beta  = (const float*)d_in[11];
    float* out = (float*)d_out;

    hipMemsetAsync(out, 0, sizeof(float), stream);   // d_out is poisoned 0xAA
    hipLaunchKernelGGL(pinn_kdv_kernel, dim3(NBLK), dim3(256), 0, stream,
                       x1, x2, W_in, b_in, W_hid, b_hid, W_out, b_out,
                       lambda_1, lambda_2, irk_alpha, irk_beta, out);
}

// Round 7
// 318.690 us; speedup vs baseline: 9.9381x; 2.0824x over previous
//
#include <hip/hip_runtime.h>

#define NPTS   100000
#define HW     50
#define DTc    0.6f
#define LBc   (-1.0f)
#define UBc    1.0f
#define PPB    40          // points per block
#define COLS   160         // 4*PPB columns (col = 4*p + channel)
#define CT     10          // 16-wide col-tiles
#define KS     72          // k-stride of H slab in fp16 units (rows 16B-multiple)
#define NBLK   5000        // 200000 / 40 exact
#define NSCALE 1024.0f     // N ~ 2e-5 is fp16-marginal; store N*1024

typedef _Float16 half4 __attribute__((ext_vector_type(4)));
typedef _Float16 half8 __attribute__((ext_vector_type(8)));
typedef float    f32x4 __attribute__((ext_vector_type(4)));

// quad_perm broadcast within each 4-lane group (pure VALU)
template <int CTRL>
__device__ __forceinline__ float qperm(float v) {
    return __int_as_float(__builtin_amdgcn_mov_dpp(__float_as_int(v), CTRL, 0xF, 0xF, true));
}
__device__ __forceinline__ float fast_tanh(float z) {
    float e = __expf(2.0f * z);
    return 1.0f - 2.0f * __builtin_amdgcn_rcpf(e + 1.0f);
}

// Weight element for GEMM layer `lay`, contraction index k, output row jrow.
// lay 0..3: W_hid^T, k==50 -> bias; lay 4: W_out^T, k==50 -> b_out;
// lay 5: alpha (row jrow, col k), jrow==50 -> beta (S row), no bias column.
__device__ __forceinline__ float wt_elem(int lay, int k, int jrow,
    const float* __restrict__ W_hid, const float* __restrict__ b_hid,
    const float* __restrict__ W_out, const float* __restrict__ b_out,
    const float* __restrict__ irk_alpha, const float* __restrict__ irk_beta) {
    if (lay == 5) {
        if (k >= HW) return 0.0f;
        if (jrow < HW)  return irk_alpha[jrow * HW + k];
        if (jrow == HW) return irk_beta[k];
        return 0.0f;
    }
    if (jrow >= HW) return 0.0f;
    if (k < HW)  return (lay == 4) ? W_out[k * HW + jrow]
                                   : W_hid[lay * HW * HW + k * HW + jrow];
    if (k == HW) return (lay == 4) ? b_out[jrow] : b_hid[lay * HW + jrow];
    return 0.0f;
}

__global__ __launch_bounds__(256, 4) void pinn_kdv_kernel(
    const float* __restrict__ x1, const float* __restrict__ x2,
    const float* __restrict__ W_in, const float* __restrict__ b_in,
    const float* __restrict__ W_hid, const float* __restrict__ b_hid,
    const float* __restrict__ W_out, const float* __restrict__ b_out,
    const float* __restrict__ lambda_1, const float* __restrict__ lambda_2,
    const float* __restrict__ irk_alpha, const float* __restrict__ irk_beta,
    float* __restrict__ out)
{
    __shared__ _Float16 Hs[COLS * KS];   // [col][k] col-major, 23,040 B
    __shared__ float red[4];

    const int tid = threadIdx.x;
    const int w  = tid >> 6;             // wave id = j-tile (output rows 16w..16w+15)
    const int l  = tid & 63;
    const int g  = l >> 4;               // k-group
    const int lc = l & 15;               // col-within-tile (B) / row-within-tile (A)
    const int c  = l & 3;                // channel of this lane's column

    const float lam1 = lambda_1[0];
    const float lam2 = __expf(lambda_2[0]);

    // ---- input stage: thread t < 160 fills column t (channel t&3 of point t>>2) ----
    if (tid < COLS) {
        const int pl = tid >> 2, ch = tid & 3;
        const int p  = blockIdx.x * PPB + pl;
        const bool b2 = p >= NPTS;
        const float x  = b2 ? x2[p - NPTS] : x1[p];
        const float xh = 2.0f * (x - LBc) / (UBc - LBc) - 1.0f;
        const float gs = 2.0f / (UBc - LBc);
        _Float16* hc = &Hs[tid * KS];
        #pragma unroll 2
        for (int j = 0; j < HW; ++j) {
            float wv = W_in[j];
            float z0 = __builtin_fmaf(xh, wv, b_in[j]);
            float z1 = gs * wv;
            float t  = fast_tanh(z0);
            float tt = t * t, s = 1.0f - tt;
            float z1sq = z1 * z1;
            float h1 = s * z1;
            float h2 = -2.0f * t * s * z1sq;
            float h3 = s * (6.0f * tt - 2.0f) * z1sq * z1;
            float val = (ch == 0) ? t : (ch == 1) ? h1 : (ch == 2) ? h2 : h3;
            hc[j] = (_Float16)val;
        }
        hc[HW] = (ch == 0) ? (_Float16)1.0f : (_Float16)0.0f;  // bias marker row
        #pragma unroll
        for (int j = HW + 1; j < KS; ++j) hc[j] = (_Float16)0.0f;  // zero pad rows
    }
    __syncthreads();

    const int jrow = 16 * w + lc;        // this lane's output-row index (A-operand)

    // ---- 6 GEMM layers: 4 hidden + output(->N) + IRK alpha ----
    // Contraction-slot relabeling k = 32*kt + 8*g + i, SAME for A and B
    // (any bijection cancels between operands) -> B-frag is one contiguous b128.
    #pragma unroll 1
    for (int lay = 0; lay < 6; ++lay) {
        half8 af[2];
        #pragma unroll
        for (int kt = 0; kt < 2; ++kt)
            #pragma unroll
            for (int i = 0; i < 8; ++i)
                af[kt][i] = (_Float16)wt_elem(lay, 32 * kt + 8 * g + i, jrow,
                                              W_hid, b_hid, W_out, b_out,
                                              irk_alpha, irk_beta);

        half4 staged[CT];                // outputs staged in regs (WAR-safe)
        #pragma unroll
        for (int ct = 0; ct < CT; ++ct) {
            const int col = 16 * ct + lc;
            const _Float16* bb = &Hs[col * KS + 8 * g];
            f32x4 acc = {0.0f, 0.0f, 0.0f, 0.0f};
            #pragma unroll
            for (int kt = 0; kt < 2; ++kt) {
                half8 bf = *(const half8*)(bb + 32 * kt);   // k = 32kt+8g+0..7
                acc = __builtin_amdgcn_mfma_f32_16x16x32_f16(af[kt], bf, acc, 0, 0, 0);
            }

            // D layout: row = 16w + 4g + r, col = 16ct + lc (m89-verified)
            half4 sv;
            if (lay < 5) {
                #pragma unroll
                for (int r = 0; r < 4; ++r) {
                    float zr  = acc[r];
                    float z0b = qperm<0x00>(zr);
                    float z1b = qperm<0x55>(zr);
                    float z2b = qperm<0xAA>(zr);
                    float z3b = qperm<0xFF>(zr);
                    float t  = fast_tanh(z0b);
                    float tt = t * t, s = 1.0f - tt;
                    float z1sq = z1b * z1b;
                    float a2 = __builtin_fmaf(-(t + t), z1sq, z2b);
                    float a3 = __builtin_fmaf(__builtin_fmaf(6.0f, tt, -2.0f), z1sq * z1b,
                               __builtin_fmaf(-6.0f * t, z1b * z2b, z3b));
                    float val;
                    if (lay == 4) {
                        // N' = -NSCALE*(lam1*U*U_x + exp(lam2)*U_xxx); channel-independent
                        val = -NSCALE * __builtin_fmaf(lam1, t * (s * z1b), lam2 * (s * a3));
                    } else {
                        float inner = (c == 1) ? z1b : (c == 2) ? a2 : a3;
                        val = (c == 0) ? t : s * inner;
                        int row = 16 * w + 4 * g + r;
                        if (row == HW) val = (c == 0) ? 1.0f : 0.0f;  // refresh marker
                    }
                    sv[r] = (_Float16)val;
                }
            } else {
                #pragma unroll
                for (int r = 0; r < 4; ++r) sv[r] = (_Float16)acc[r];  // v'
            }
            staged[ct] = sv;
        }
        __syncthreads();                 // all B-reads done before overwriting H
        #pragma unroll
        for (int ct = 0; ct < CT; ++ct) {
            const int col = 16 * ct + lc;
            *(half4*)&Hs[col * KS + 16 * w + 4 * g] = staged[ct];
        }
        __syncthreads();
    }

    // ---- residual + loss: Hs holds v' rows 0..49, S' row 50, per col ----
    float acc = 0.0f;
    if (tid < COLS) {
        const int pl = tid >> 2, ch = tid & 3;
        const int p  = blockIdx.x * PPB + pl;
        const bool b2 = p >= NPTS;
        const _Float16* vc = &Hs[(4 * pl) * KS];   // channel-0 column of this point
        const float Sp = (float)vc[HW];
        const int i0 = 13 * ch;
        const int i1 = (ch == 3) ? HW : i0 + 13;   // rows split 13/13/13/11
        for (int i = i0; i < i1; ++i) {
            float vv = (float)vc[i];
            float rr = b2 ? (Sp - vv) : vv;
            acc = __builtin_fmaf(rr, rr, acc);
        }
    }
    #pragma unroll
    for (int off = 1; off < 64; off <<= 1)
        acc += __shfl_xor(acc, off);
    if (l == 0) red[w] = acc;
    __syncthreads();
    if (tid == 0)
        atomicAdd(out, (red[0] + red[1] + red[2] + red[3]) *
                       (DTc * DTc / (NSCALE * NSCALE)));
}

extern "C" void kernel_launch(void* const* d_in, const int* in_sizes, int n_in,
                              void* d_out, int out_size, void* d_ws, size_t ws_size,
                              hipStream_t stream) {
    const float* x1        = (const float*)d_in[0];
    const float* x2        = (const float*)d_in[1];
    const float* W_in      = (const float*)d_in[2];
    const float* b_in      = (const float*)d_in[3];
    const float* W_hid     = (const float*)d_in[4];
    const float* b_hid     = (const float*)d_in[5];
    const float* W_out     = (const float*)d_in[6];
    const float* b_out     = (const float*)d_in[7];
    const float* lambda_1  = (const float*)d_in[8];
    const float* lambda_2  = (const float*)d_in[9];
    const float* irk_alpha = (const float*)d_in[10];
    const float* irk_beta  = (const float*)d_in[11];
    float* out = (float*)d_out;

    hipMemsetAsync(out, 0, sizeof(float), stream);   // d_out is poisoned 0xAA
    hipLaunchKernelGGL(pinn_kdv_kernel, dim3(NBLK), dim3(256), 0, stream,
                       x1, x2, W_in, b_in, W_hid, b_hid, W_out, b_out,
                       lambda_1, lambda_2, irk_alpha, irk_beta, out);
}

// Round 9
// 215.950 us; speedup vs baseline: 14.6662x; 1.4758x over previous
//
#include <hip/hip_runtime.h>

#define NPTS   100000
#define HW     50
#define DTc    0.6f
#define LBc   (-1.0f)
#define UBc    1.0f
#define PPB    40          // points per block
#define COLS   160         // 4*PPB columns (col = 4*p + channel)
#define CT     10          // 16-wide pc-tiles (4 points each)
#define KS     76          // k-stride in halves: 152 B rows -> 38 dw stride, 2-way banks (free)
#define NBLK   5000        // 200000 / 40 exact
#define NSCALE 1024.0f     // N ~ 2e-5 is fp16-marginal; store N*1024

typedef _Float16 half4 __attribute__((ext_vector_type(4)));
typedef _Float16 half8 __attribute__((ext_vector_type(8)));
typedef float    f32x4 __attribute__((ext_vector_type(4)));

__device__ __forceinline__ float fast_tanh(float z) {
    float e = __expf(2.0f * z);
    return 1.0f - 2.0f * __builtin_amdgcn_rcpf(e + 1.0f);
}

// Weight element for GEMM layer `lay`, contraction index k, output index jrow.
// lay 0..3: W_hid^T, k==50 -> bias; lay 4: W_out^T, k==50 -> b_out;
// lay 5: alpha (row jrow, col k), jrow==50 -> beta (S row), no bias column.
__device__ __forceinline__ float wt_elem(int lay, int k, int jrow,
    const float* __restrict__ W_hid, const float* __restrict__ b_hid,
    const float* __restrict__ W_out, const float* __restrict__ b_out,
    const float* __restrict__ irk_alpha, const float* __restrict__ irk_beta) {
    if (lay == 5) {
        if (k >= HW) return 0.0f;
        if (jrow < HW)  return irk_alpha[jrow * HW + k];
        if (jrow == HW) return irk_beta[k];
        return 0.0f;
    }
    if (jrow >= HW) return 0.0f;
    if (k < HW)  return (lay == 4) ? W_out[k * HW + jrow]
                                   : W_hid[lay * HW * HW + k * HW + jrow];
    if (k == HW) return (lay == 4) ? b_out[jrow] : b_hid[lay * HW + jrow];
    return 0.0f;
}

__global__ __launch_bounds__(256, 4) void pinn_kdv_kernel(
    const float* __restrict__ x1, const float* __restrict__ x2,
    const float* __restrict__ W_in, const float* __restrict__ b_in,
    const float* __restrict__ W_hid, const float* __restrict__ b_hid,
    const float* __restrict__ W_out, const float* __restrict__ b_out,
    const float* __restrict__ lambda_1, const float* __restrict__ lambda_2,
    const float* __restrict__ irk_alpha, const float* __restrict__ irk_beta,
    float* __restrict__ out)
{
    __shared__ __align__(16) _Float16 Hs[COLS * KS];  // [pc][k], 24,320 B
    __shared__ float red[4];

    const int tid = threadIdx.x;
    const int w  = tid >> 6;             // wave id: owns output cols j = 16w..16w+15
    const int l  = tid & 63;
    const int g  = l >> 4;               // k-slot group / point-within-tile
    const int lc = l & 15;               // A-row (pc) / B-col (j) within tile
    const int j  = 16 * w + lc;          // this lane's output neuron / IRK row index

    const float lam1 = lambda_1[0];
    const float lam2 = __expf(lambda_2[0]);

    // ---- input stage: thread t < 160 fills column t (channel t&3 of point t>>2) ----
    if (tid < COLS) {
        const int pl = tid >> 2, ch = tid & 3;
        const int p  = blockIdx.x * PPB + pl;
        const bool b2 = p >= NPTS;
        const float x  = b2 ? x2[p - NPTS] : x1[p];
        const float xh = 2.0f * (x - LBc) / (UBc - LBc) - 1.0f;
        const float gs = 2.0f / (UBc - LBc);
        _Float16* hc = &Hs[tid * KS];
        #pragma unroll 2
        for (int jj = 0; jj < HW; ++jj) {
            float wv = W_in[jj];
            float z0 = __builtin_fmaf(xh, wv, b_in[jj]);
            float z1 = gs * wv;
            float t  = fast_tanh(z0);
            float tt = t * t, s = 1.0f - tt;
            float z1sq = z1 * z1;
            float h1 = s * z1;
            float h2 = -2.0f * t * s * z1sq;
            float h3 = s * (6.0f * tt - 2.0f) * z1sq * z1;
            float val = (ch == 0) ? t : (ch == 1) ? h1 : (ch == 2) ? h2 : h3;
            hc[jj] = (_Float16)val;
        }
        hc[HW] = (ch == 0) ? (_Float16)1.0f : (_Float16)0.0f;  // bias marker row
        #pragma unroll
        for (int jj = HW + 1; jj < KS; ++jj) hc[jj] = (_Float16)0.0f;
    }
    __syncthreads();

    // ---- 6 GEMM layers. D = H^T x W: row = pc (4 channels of one point in the
    // 4 acc regs), col = j. Nonlinear is fully in-lane: no qperm, no select. ----
    #pragma unroll 1
    for (int lay = 0; lay < 6; ++lay) {
        half8 wf[2];                     // B-operand: weight fragment (slot k=32kt+8g+i)
        #pragma unroll
        for (int kt = 0; kt < 2; ++kt)
            #pragma unroll
            for (int i = 0; i < 8; ++i)
                wf[kt][i] = (_Float16)wt_elem(lay, 32 * kt + 8 * g + i, j,
                                              W_hid, b_hid, W_out, b_out,
                                              irk_alpha, irk_beta);

        half4 staged[CT];                // per pt: 4 channel h's (lay<4) or 1 value
        #pragma unroll
        for (int pt = 0; pt < CT; ++pt) {
            // A-operand: H^T fragment, row pc = 16pt+lc, slots k=32kt+8g+i.
            // Two b64 reads (8B-aligned; KS=76 -> stride 38 dw -> 2-way banks, free).
            const _Float16* bb = &Hs[(16 * pt + lc) * KS + 8 * g];
            f32x4 acc = {0.0f, 0.0f, 0.0f, 0.0f};
            #pragma unroll
            for (int kt = 0; kt < 2; ++kt) {
                half4 lo = *(const half4*)(bb + 32 * kt);
                half4 hi = *(const half4*)(bb + 32 * kt + 4);
                half8 hf;
                #pragma unroll
                for (int i = 0; i < 4; ++i) { hf[i] = lo[i]; hf[i + 4] = hi[i]; }
                acc = __builtin_amdgcn_mfma_f32_16x16x32_f16(hf, wf[kt], acc, 0, 0, 0);
            }
            // acc[r] = z-channel r of point p = 4pt+g, neuron/row j
            float z0 = acc[0], z1 = acc[1], z2 = acc[2], z3 = acc[3];
            half4 sv = {(_Float16)0.0f, (_Float16)0.0f, (_Float16)0.0f, (_Float16)0.0f};
            if (lay < 5) {
                float t  = fast_tanh(z0);
                float tt = t * t, s = 1.0f - tt;
                float z1sq = z1 * z1;
                float a2 = __builtin_fmaf(-(t + t), z1sq, z2);
                float a3 = __builtin_fmaf(__builtin_fmaf(6.0f, tt, -2.0f), z1sq * z1,
                           __builtin_fmaf(-6.0f * t, z1 * z2, z3));
                if (lay < 4) {
                    sv[0] = (_Float16)t;
                    sv[1] = (_Float16)(s * z1);
                    sv[2] = (_Float16)(s * a2);
                    sv[3] = (_Float16)(s * a3);
                    if (j == HW) {       // refresh bias marker row
                        sv[0] = (_Float16)1.0f;
                        sv[1] = sv[2] = sv[3] = (_Float16)0.0f;
                    }
                } else {
                    // N' = -NSCALE*(lam1*U*U_x + exp(lam2)*U_xxx), one value per point
                    sv[0] = (_Float16)(-NSCALE *
                            __builtin_fmaf(lam1, t * (s * z1), lam2 * (s * a3)));
                }
            } else {
                sv[0] = (_Float16)z0;    // v'_j for point p (channel-0 row)
            }
            staged[pt] = sv;
        }
        __syncthreads();                 // all reads of Hs done before overwrite
        #pragma unroll
        for (int pt = 0; pt < CT; ++pt) {
            _Float16* wp = &Hs[(4 * (4 * pt + g)) * KS + j];  // channel-0 col, row j
            if (lay < 4) {               // scatter 4 channels (stride KS cols)
                wp[0]      = staged[pt][0];
                wp[KS]     = staged[pt][1];
                wp[2 * KS] = staged[pt][2];
                wp[3 * KS] = staged[pt][3];
            } else {
                wp[0] = staged[pt][0];   // N' / v' into channel-0 column only
            }
        }
        __syncthreads();
    }

    // ---- residual + loss: channel-0 cols hold v' rows 0..49, S' at row 50 ----
    float acc = 0.0f;
    if (tid < COLS) {
        const int pl = tid >> 2, ch = tid & 3;
        const int p  = blockIdx.x * PPB + pl;
        const bool b2 = p >= NPTS;
        const _Float16* vc = &Hs[(4 * pl) * KS];
        const float Sp = (float)vc[HW];
        const int i0 = 13 * ch;
        const int i1 = (ch == 3) ? HW : i0 + 13;   // rows split 13/13/13/11
        for (int i = i0; i < i1; ++i) {
            float vv = (float)vc[i];
            float rr = b2 ? (Sp - vv) : vv;
            acc = __builtin_fmaf(rr, rr, acc);
        }
    }
    #pragma unroll
    for (int off = 1; off < 64; off <<= 1)
        acc += __shfl_xor(acc, off);
    if (l == 0) red[w] = acc;
    __syncthreads();
    if (tid == 0)
        atomicAdd(out, (red[0] + red[1] + red[2] + red[3]) *
                       (DTc * DTc / (NSCALE * NSCALE)));
}

extern "C" void kernel_launch(void* const* d_in, const int* in_sizes, int n_in,
                              void* d_out, int out_size, void* d_ws, size_t ws_size,
                              hipStream_t stream) {
    const float* x1        = (const float*)d_in[0];
    const float* x2        = (const float*)d_in[1];
    const float* W_in      = (const float*)d_in[2];
    const float* b_in      = (const float*)d_in[3];
    const float* W_hid     = (const float*)d_in[4];
    const float* b_hid     = (const float*)d_in[5];
    const float* W_out     = (const float*)d_in[6];
    const float* b_out     = (const float*)d_in[7];
    const float* lambda_1  = (const float*)d_in[8];
    const float* lambda_2  = (const float*)d_in[9];
    const float* irk_alpha = (const float*)d_in[10];
    const float* irk_beta  = (const float*)d_in[11];
    float* out = (float*)d_out;

    hipMemsetAsync(out, 0, sizeof(float), stream);   // d_out is poisoned 0xAA
    hipLaunchKernelGGL(pinn_kdv_kernel, dim3(NBLK), dim3(256), 0, stream,
                       x1, x2, W_in, b_in, W_hid, b_hid, W_out, b_out,
                       lambda_1, lambda_2, irk_alpha, irk_beta, out);
}